// Round 1
// 315.875 us; speedup vs baseline: 1.0294x; 1.0294x over previous
//
#include <hip/hip_runtime.h>
#include <math.h>

#define NTOK 16384
#define HDIM 2048
#define NEXP 64
#define KK   32
#define TAU  5e-5f
#define LGT  16384   // logits row stride (tokens), layout [e][t]
#define MAXB 2048    // bucket capacity per expert (mean 256, 112 sigma margin)
#define KPAD 40      // LDS bf16 row pad (80 B rows: 16B-aligned, conflict-free b128 frag reads)
#define LTS  132     // epilogue LDS tile row stride (floats)

typedef __attribute__((ext_vector_type(8))) short short8;
typedef __attribute__((ext_vector_type(4))) float f32x4;
typedef __attribute__((ext_vector_type(2))) unsigned int uint2v;

// ws layout (4-byte units):
// [0..64)              inv_nc (f32)
// [64..128)            counts/cursor (i32)
// [128..192)           nflag + pad (i32)
// [192..16576)         route  (i32)
// [16576..32960)       flags  (i32)
// [32960..164032)      sums   (f32, 64x2048)
// [164032..180416)     xnorm2 (f32, 16384)
// [180416..1228992)    logits (f32, 64x16384)
// [1228992..1360064)   bn     (f32, 64x2048)
// [1360064..1491136)   bucket (i32, 64x2048)    total ~5.96 MB

__global__ __launch_bounds__(256)
void zero_kernel(float* p, int n) {
  int i = blockIdx.x * 256 + threadIdx.x;
  if (i < n) p[i] = 0.0f;
}

__device__ __forceinline__ float block_reduce_sum(float v, float* red) {
  #pragma unroll
  for (int o = 32; o > 0; o >>= 1) v += __shfl_down(v, o, 64);
  int lane = threadIdx.x & 63;
  int wid  = threadIdx.x >> 6;
  if (lane == 0) red[wid] = v;
  __syncthreads();
  float s = red[0] + red[1] + red[2] + red[3];
  __syncthreads();
  return s;
}

__device__ __forceinline__ double block_reduce_sum_f64(double v, double* red) {
  const int tid = threadIdx.x;
  red[tid] = v;
  __syncthreads();
  if (tid < 128) red[tid] += red[tid + 128];
  __syncthreads();
  if (tid < 64)  red[tid] += red[tid + 64];
  __syncthreads();
  double s = 0.0;
  if (tid < 64) {
    s = red[tid];
    #pragma unroll
    for (int o = 32; o > 0; o >>= 1) s += __shfl_down(s, o, 64);
  }
  if (tid == 0) red[0] = s;
  __syncthreads();
  s = red[0];
  __syncthreads();
  return s;
}

__global__ __launch_bounds__(256)
void cnorm_kernel(const float* __restrict__ c, float* __restrict__ inv_nc) {
  __shared__ float red[4];
  int e = blockIdx.x;
  float ss = 0.f;
  #pragma unroll
  for (int j = 0; j < 8; ++j) {
    float v = c[e * HDIM + threadIdx.x + j * 256];
    ss += v * v;
  }
  float tot = block_reduce_sum(ss, red);
  if (threadIdx.x == 0) inv_nc[e] = 1.0f / fmaxf(sqrtf(tot), 1e-12f);
}

// fp64 center norms -> fp32, materialize bn[e][k] = fl32(c/nc32) (numpy's centers_n).
__global__ __launch_bounds__(256)
void cnormalize_kernel(const float* __restrict__ c, float* __restrict__ bn) {
  __shared__ double redd[256];
  __shared__ float s_nc;
  const int e = blockIdx.x;
  const int tid = threadIdx.x;
  const float* cr = c + (size_t)e * HDIM;
  double acc = 0.0;
  #pragma unroll
  for (int i = 0; i < 8; ++i) {
    double v = (double)cr[tid + 256 * i];
    acc += v * v;
  }
  double cn = block_reduce_sum_f64(acc, redd);
  if (tid == 0) s_nc = (float)fmax(sqrt(cn), 1e-12);
  __syncthreads();
  const double nc = (double)s_nc;
  #pragma unroll
  for (int i = 0; i < 8; ++i) {
    int k = tid + 256 * i;
    bn[(size_t)e * HDIM + k] = (float)((double)cr[k] / nc);
  }
}

// split fp32 pair into bf16 hi (truncation) + bf16 lo (truncated residual), packed 2-wide.
__device__ __forceinline__ void cvt2(float v0, float v1, unsigned &hi, unsigned &lo) {
  unsigned u0 = __float_as_uint(v0);
  unsigned u1 = __float_as_uint(v1);
  unsigned h0 = u0 & 0xffff0000u;
  unsigned h1 = u1 & 0xffff0000u;
  float r0 = v0 - __uint_as_float(h0);
  float r1 = v1 - __uint_as_float(h1);
  hi = (u0 >> 16) | h1;
  lo = (__float_as_uint(r0) >> 16) | (__float_as_uint(r1) & 0xffff0000u);
}

// K-split MFMA GEMM (bf16x3 split-precision): block = 128 tokens x 64 experts x 512 K.
// grid = 128 mtiles x 4 ksplits. dot = hi*hi + hi*lo + lo*hi, fp32 MFMA accumulate.
__global__ __launch_bounds__(256)
void gemm_kernel(const float* __restrict__ x, const float* __restrict__ c,
                 float* __restrict__ logits, float* __restrict__ xnorm2) {
  __shared__ __align__(16) unsigned short smem[15360];   // 30 KB
  unsigned short (*Ah)[KPAD] = (unsigned short (*)[KPAD])(smem);          // 128x40
  unsigned short (*Al)[KPAD] = (unsigned short (*)[KPAD])(smem + 5120);   // 128x40
  unsigned short (*Bh)[KPAD] = (unsigned short (*)[KPAD])(smem + 10240);  // 64x40
  unsigned short (*Bl)[KPAD] = (unsigned short (*)[KPAD])(smem + 12800);  // 64x40

  const int tid  = threadIdx.x;
  const int mt   = blockIdx.x >> 2;
  const int ks   = blockIdx.x & 3;
  const int t0   = mt * 128;
  const int kb   = ks * 512;
  const int sr   = tid >> 1;          // A stage: row, 2 threads/row
  const int sq   = (tid & 1) * 16;    // A stage: 16-col half of 32-chunk
  const int er   = tid >> 2;          // B stage: expert row, 4 threads/row
  const int eq   = (tid & 3) * 8;     // B stage: 8-col quarter
  const int lane = tid & 63;
  const int w    = tid >> 6;          // wave -> 32-token slice
  const int fr   = lane & 15;         // frag row (A row / B col)
  const int fk   = (lane >> 4) * 8;   // frag k offset (8 consecutive k per lane)

  const float* xrow = x + (size_t)(t0 + sr) * HDIM + kb + sq;
  const float* crow = c + (size_t)er * HDIM + kb + eq;

  f32x4 xp[4], cp[2];
  #pragma unroll
  for (int i = 0; i < 4; ++i) xp[i] = *(const f32x4*)(xrow + 4 * i);
  #pragma unroll
  for (int i = 0; i < 2; ++i) cp[i] = *(const f32x4*)(crow + 4 * i);

  f32x4 acc[2][4];
  #pragma unroll
  for (int mi = 0; mi < 2; ++mi)
    #pragma unroll
    for (int ni = 0; ni < 4; ++ni)
      acc[mi][ni] = (f32x4){0.f, 0.f, 0.f, 0.f};
  float nacc = 0.f;

  for (int it = 0; it < 16; ++it) {
    __syncthreads();
    #pragma unroll
    for (int i = 0; i < 4; ++i) {
      unsigned h01, l01, h23, l23;
      cvt2(xp[i].x, xp[i].y, h01, l01);
      cvt2(xp[i].z, xp[i].w, h23, l23);
      *(uint2v*)&Ah[sr][sq + 4 * i] = (uint2v){h01, h23};
      *(uint2v*)&Al[sr][sq + 4 * i] = (uint2v){l01, l23};
      nacc += xp[i].x*xp[i].x + xp[i].y*xp[i].y + xp[i].z*xp[i].z + xp[i].w*xp[i].w;
    }
    #pragma unroll
    for (int i = 0; i < 2; ++i) {
      unsigned h01, l01, h23, l23;
      cvt2(cp[i].x, cp[i].y, h01, l01);
      cvt2(cp[i].z, cp[i].w, h23, l23);
      *(uint2v*)&Bh[er][eq + 4 * i] = (uint2v){h01, h23};
      *(uint2v*)&Bl[er][eq + 4 * i] = (uint2v){l01, l23};
    }
    __syncthreads();
    if (it < 15) {
      const float* xn = xrow + (it + 1) * KK;
      const float* cn = crow + (it + 1) * KK;
      #pragma unroll
      for (int i = 0; i < 4; ++i) xp[i] = *(const f32x4*)(xn + 4 * i);
      #pragma unroll
      for (int i = 0; i < 2; ++i) cp[i] = *(const f32x4*)(cn + 4 * i);
    }
    short8 ah0 = *(const short8*)&Ah[w * 32 + fr][fk];
    short8 ah1 = *(const short8*)&Ah[w * 32 + 16 + fr][fk];
    short8 al0 = *(const short8*)&Al[w * 32 + fr][fk];
    short8 al1 = *(const short8*)&Al[w * 32 + 16 + fr][fk];
    #pragma unroll
    for (int ni = 0; ni < 4; ++ni) {
      short8 bh = *(const short8*)&Bh[ni * 16 + fr][fk];
      short8 bl = *(const short8*)&Bl[ni * 16 + fr][fk];
      acc[0][ni] = __builtin_amdgcn_mfma_f32_16x16x32_bf16(ah0, bh, acc[0][ni], 0, 0, 0);
      acc[0][ni] = __builtin_amdgcn_mfma_f32_16x16x32_bf16(ah0, bl, acc[0][ni], 0, 0, 0);
      acc[0][ni] = __builtin_amdgcn_mfma_f32_16x16x32_bf16(al0, bh, acc[0][ni], 0, 0, 0);
      acc[1][ni] = __builtin_amdgcn_mfma_f32_16x16x32_bf16(ah1, bh, acc[1][ni], 0, 0, 0);
      acc[1][ni] = __builtin_amdgcn_mfma_f32_16x16x32_bf16(ah1, bl, acc[1][ni], 0, 0, 0);
      acc[1][ni] = __builtin_amdgcn_mfma_f32_16x16x32_bf16(al1, bh, acc[1][ni], 0, 0, 0);
    }
  }

  atomicAdd(&xnorm2[t0 + sr], nacc);

  // epilogue: transpose frags through LDS (32 experts per half), coalesced atomic add.
  float* lt = (float*)smem;
  #pragma unroll
  for (int eh = 0; eh < 2; ++eh) {
    __syncthreads();
    #pragma unroll
    for (int ni2 = 0; ni2 < 2; ++ni2) {
      const int ni = eh * 2 + ni2;
      const int e  = ni2 * 16 + fr;
      #pragma unroll
      for (int mi = 0; mi < 2; ++mi) {
        const int t = w * 32 + mi * 16 + (lane >> 4) * 4;
        *(f32x4*)&lt[e * LTS + t] = acc[mi][ni];
      }
    }
    __syncthreads();
    #pragma unroll
    for (int n = 0; n < 16; ++n) {
      const int f = tid + n * 256;
      const int e = f >> 7;
      const int t = f & 127;
      atomicAdd(&logits[(size_t)(e + eh * 32) * LGT + t0 + t], lt[e * LTS + t]);
    }
  }
}

// softmax / top-2 / flag. Thread = token. 64-thread blocks so all 256 CUs engage.
__global__ __launch_bounds__(64)
void softmax_kernel(const float* __restrict__ logits, const float* __restrict__ xnorm2,
                    const float* __restrict__ inv_nc, float* __restrict__ out,
                    int* __restrict__ route, int* __restrict__ nflag,
                    int* __restrict__ flags) {
  __shared__ float snc[NEXP];
  const int tid = threadIdx.x;
  snc[tid] = inv_nc[tid];
  __syncthreads();
  const int t = blockIdx.x * 64 + tid;
  const float inv_nx = 1.0f / fmaxf(sqrtf(xnorm2[t]), 1e-12f);
  float lv[NEXP];
  #pragma unroll
  for (int e = 0; e < NEXP; ++e)
    lv[e] = logits[(size_t)e * LGT + t] * snc[e] * inv_nx;
  float m1 = -1e30f, m2 = -1e30f, m3 = -1e30f;
  int i1 = 0, i2 = 0;
  #pragma unroll
  for (int e = 0; e < NEXP; ++e) {
    float l = lv[e];
    if (l > m1)      { m3 = m2; m2 = m1; i2 = i1; m1 = l; i1 = e; }
    else if (l > m2) { m3 = m2; m2 = l; i2 = e; }
    else if (l > m3) { m3 = l; }
  }
  float Z = 0.f;
  #pragma unroll
  for (int e = 0; e < NEXP; ++e) Z += expf(lv[e] - m1);
  const float p1w = 1.0f / Z;
  const float p2w = expf(m2 - m1) / Z;
  const float s   = p1w + p2w + 1e-9f;
  out[t * 2 + 0] = (float)i1;
  out[t * 2 + 1] = (float)i2;
  out[2 * NTOK + t * 2 + 0] = p1w / s;
  out[2 * NTOK + t * 2 + 1] = p2w / s;
  route[t] = i1;
  if ((m1 - m2) < TAU || (m2 - m3) < TAU) {
    int idx = atomicAdd(nflag, 1);
    flags[idx] = t;
  }
}

// Refine v2 (R8, known-good): block per flagged token.
__global__ __launch_bounds__(256)
void refine_np_kernel(const float* __restrict__ x, const float* __restrict__ bn,
                      float* __restrict__ out, int* __restrict__ route,
                      const int* __restrict__ nflag, const int* __restrict__ flags) {
  __shared__ float a_lds[HDIM];
  __shared__ double redd[256];
  __shared__ float lf[NEXP];
  __shared__ float s_nx;
  const int tid  = threadIdx.x;
  const int lane = tid & 63;
  const int w    = tid >> 6;
  const int n = *nflag;
  for (int j = blockIdx.x; j < n; j += gridDim.x) {
    const int t = flags[j];
    const float* xr = x + (size_t)t * HDIM;
    double xacc = 0.0;
    #pragma unroll
    for (int i = 0; i < 8; ++i) {
      double v = (double)xr[tid + 256 * i];
      xacc += v * v;
    }
    double xn = block_reduce_sum_f64(xacc, redd);
    if (tid == 0) s_nx = (float)fmax(sqrt(xn), 1e-12);
    __syncthreads();
    const double nx = (double)s_nx;
    #pragma unroll
    for (int i = 0; i < 8; ++i) {
      int k = tid + 256 * i;
      a_lds[k] = (float)((double)xr[k] / nx);
    }
    __syncthreads();
    #pragma unroll 1
    for (int ei = 0; ei < 16; ++ei) {
      const int e = w * 16 + ei;
      const float* br = bn + (size_t)e * HDIM;
      double d = 0.0;
      #pragma unroll 8
      for (int i = 0; i < 32; ++i) {
        int k = lane + 64 * i;
        d += (double)a_lds[k] * (double)br[k];
      }
      #pragma unroll
      for (int o = 32; o > 0; o >>= 1) d += __shfl_down(d, o, 64);
      if (lane == 0) lf[e] = (float)d;
    }
    __syncthreads();
    if (tid == 0) {
      float m32 = lf[0];
      for (int ee = 1; ee < NEXP; ++ee) m32 = fmaxf(m32, lf[ee]);
      float ex[NEXP];
      for (int ee = 0; ee < NEXP; ++ee)
        ex[ee] = (float)exp((double)(lf[ee] - m32));
      float r[8];
      #pragma unroll
      for (int q = 0; q < 8; ++q) r[q] = ex[q];
      for (int i = 8; i < NEXP; i += 8)
        #pragma unroll
        for (int q = 0; q < 8; ++q) r[q] += ex[i + q];
      const float Z = ((r[0] + r[1]) + (r[2] + r[3])) + ((r[4] + r[5]) + (r[6] + r[7]));
      float p1 = -1.f, p2 = -1.f;
      int i1 = 0, i2 = 0;
      for (int ee = 0; ee < NEXP; ++ee) {
        float p = ex[ee] / Z;
        if (p > p1)      { p2 = p1; i2 = i1; p1 = p; i1 = ee; }
        else if (p > p2) { p2 = p; i2 = ee; }
      }
      const float s = (p1 + p2) + 1e-9f;
      out[t * 2 + 0] = (float)i1;
      out[t * 2 + 1] = (float)i2;
      out[2 * NTOK + t * 2 + 0] = p1 / s;
      out[2 * NTOK + t * 2 + 1] = p2 / s;
      route[t] = i1;
    }
    __syncthreads();
  }
}

// slow fallback refine (no bn dependency) for small-ws path
__global__ __launch_bounds__(64)
void refine_np_slow(const float* __restrict__ x, const float* __restrict__ c,
                    float* __restrict__ out, int* __restrict__ route,
                    const int* __restrict__ nflag, const int* __restrict__ flags) {
  __shared__ float lf[NEXP];
  const int e = threadIdx.x;
  const int n = *nflag;
  for (int j = blockIdx.x; j < n; j += gridDim.x) {
    const int t = flags[j];
    const float* xr = x + (size_t)t * HDIM;
    const float* cr = c + (size_t)e * HDIM;
    double xn = 0.0, cn = 0.0;
    for (int k = 0; k < HDIM; ++k) {
      double xv = (double)xr[k];
      double cv = (double)cr[k];
      xn += xv * xv;
      cn += cv * cv;
    }
    const float nx32 = (float)fmax(sqrt(xn), 1e-12);
    const float nc32 = (float)fmax(sqrt(cn), 1e-12);
    double d = 0.0;
    for (int k = 0; k < HDIM; ++k) {
      float a = (float)((double)xr[k] / (double)nx32);
      float b = (float)((double)cr[k] / (double)nc32);
      d += (double)a * (double)b;
    }
    lf[e] = (float)d;
    __syncthreads();
    if (e == 0) {
      float m32 = lf[0];
      for (int ee = 1; ee < NEXP; ++ee) m32 = fmaxf(m32, lf[ee]);
      float ex[NEXP];
      for (int ee = 0; ee < NEXP; ++ee)
        ex[ee] = (float)exp((double)(lf[ee] - m32));
      float r[8];
      #pragma unroll
      for (int q = 0; q < 8; ++q) r[q] = ex[q];
      for (int i = 8; i < NEXP; i += 8)
        #pragma unroll
        for (int q = 0; q < 8; ++q) r[q] += ex[i + q];
      const float Z = ((r[0] + r[1]) + (r[2] + r[3])) + ((r[4] + r[5]) + (r[6] + r[7]));
      float p1 = -1.f, p2 = -1.f;
      int i1 = 0, i2 = 0;
      for (int ee = 0; ee < NEXP; ++ee) {
        float p = ex[ee] / Z;
        if (p > p1)      { p2 = p1; i2 = i1; p1 = p; i1 = ee; }
        else if (p > p2) { p2 = p; i2 = ee; }
      }
      const float s = (p1 + p2) + 1e-9f;
      out[t * 2 + 0] = (float)i1;
      out[t * 2 + 1] = (float)i2;
      out[2 * NTOK + t * 2 + 0] = p1 / s;
      out[2 * NTOK + t * 2 + 1] = p2 / s;
      route[t] = i1;
    }
    __syncthreads();
  }
}

// Bucket scatter: cursor[e] counts tokens (== counts), bucket[e][pos] = t.
__global__ __launch_bounds__(256)
void scatter_kernel(const int* __restrict__ route, int* __restrict__ cursor,
                    int* __restrict__ bucket) {
  const int t = blockIdx.x * 256 + threadIdx.x;
  const int e = route[t];
  const int pos = atomicAdd(&cursor[e], 1);
  if (pos < MAXB) bucket[e * MAXB + pos] = t;
}

// Dense per-expert sum: block = (expert, h-chunk). No atomics, direct store.
__global__ __launch_bounds__(256)
void segsum_dense(const float* __restrict__ x, const int* __restrict__ cursor,
                  const int* __restrict__ bucket, float* __restrict__ sums) {
  __shared__ int ts[MAXB];
  const int e   = blockIdx.x >> 3;
  const int hc  = blockIdx.x & 7;
  const int hb  = hc * 256;
  const int tid = threadIdx.x;
  int n = cursor[e];
  if (n > MAXB) n = MAXB;
  for (int i = tid; i < n; i += 256) ts[i] = bucket[e * MAXB + i];
  __syncthreads();
  float a[8];
  #pragma unroll
  for (int q = 0; q < 8; ++q) a[q] = 0.f;
  int i = 0;
  for (; i + 7 < n; i += 8) {
    #pragma unroll
    for (int q = 0; q < 8; ++q)
      a[q] += x[(size_t)ts[i + q] * HDIM + hb + tid];
  }
  for (; i < n; ++i) a[0] += x[(size_t)ts[i] * HDIM + hb + tid];
  const float s = ((a[0] + a[1]) + (a[2] + a[3])) + ((a[4] + a[5]) + (a[6] + a[7]));
  sums[e * HDIM + hb + tid] = s;
}

__global__ __launch_bounds__(256)
void finalize_kernel(const float* __restrict__ c, const float* __restrict__ sums,
                     const int* __restrict__ counts, float* __restrict__ out) {
  __shared__ float red[4];
  const int e = blockIdx.x;
  const int tid = threadIdx.x;
  const float cnt = (float)counts[e];
  const float minv = 1.0f / (cnt + 1e-6f);
  float u[8], cv[8];
  float ss = 0.f;
  #pragma unroll
  for (int j = 0; j < 8; ++j) {
    int h = tid + j * 256;
    cv[j] = c[e * HDIM + h];
    float mean = sums[e * HDIM + h] * minv;
    u[j] = 0.9f * cv[j] + 0.1f * mean;
    ss += u[j] * u[j];
  }
  float tot = block_reduce_sum(ss, red);
  float sc = 1.0f / fmaxf(sqrtf(tot), 1e-12f);
  const bool nz = cnt > 0.f;
  #pragma unroll
  for (int j = 0; j < 8; ++j) {
    int h = tid + j * 256;
    out[4 * NTOK + e * HDIM + h] = nz ? u[j] * sc : cv[j];
  }
}

// ---- fallback path kernels (small ws): R5 router + old segsum ----
__global__ __launch_bounds__(256)
void router_kernel(const float* __restrict__ x, const float* __restrict__ c,
                   const float* __restrict__ inv_nc, float* __restrict__ out,
                   int* __restrict__ route, int* __restrict__ nflag,
                   int* __restrict__ flags) {
  __shared__ __align__(16) float xs[64][36];
  __shared__ float lgs[64][67];
  const int tid  = threadIdx.x;
  const int lane = tid & 63;
  const int w    = tid >> 6;
  const int t0   = blockIdx.x * 64;
  const int e0   = __builtin_amdgcn_readfirstlane(w * 16);
  const float* cb = c + (size_t)e0 * HDIM;
  const int st = tid >> 3;
  const int sk = (tid & 7) * 4;
  float acc[16];
  #pragma unroll
  for (int e = 0; e < 16; ++e) acc[e] = 0.f;
  float nacc = 0.f;
  float4 p0 = *(const float4*)&x[(size_t)(t0 + st)      * HDIM + sk];
  float4 p1 = *(const float4*)&x[(size_t)(t0 + st + 32) * HDIM + sk];
  for (int k0 = 0; k0 < HDIM; k0 += 32) {
    __syncthreads();
    *(float4*)&xs[st][sk]      = p0;
    *(float4*)&xs[st + 32][sk] = p1;
    __syncthreads();
    const int kn = k0 + 32;
    if (kn < HDIM) {
      p0 = *(const float4*)&x[(size_t)(t0 + st)      * HDIM + kn + sk];
      p1 = *(const float4*)&x[(size_t)(t0 + st + 32) * HDIM + kn + sk];
    }
    float a[32];
    #pragma unroll
    for (int j = 0; j < 32; j += 4) {
      float4 v = *(const float4*)&xs[lane][j];
      a[j] = v.x; a[j+1] = v.y; a[j+2] = v.z; a[j+3] = v.w;
    }
    if (w == 0) {
      #pragma unroll
      for (int j = 0; j < 32; ++j) nacc += a[j] * a[j];
    }
    #pragma unroll
    for (int e = 0; e < 16; ++e) {
      const float* br = cb + (size_t)e * HDIM + k0;
      #pragma unroll
      for (int j = 0; j < 32; j += 4) {
        float4 bv = *(const float4*)&br[j];
        acc[e] += a[j]*bv.x + a[j+1]*bv.y + a[j+2]*bv.z + a[j+3]*bv.w;
      }
    }
  }
  #pragma unroll
  for (int e = 0; e < 16; ++e) lgs[lane][e0 + e] = acc[e] * inv_nc[e0 + e];
  __syncthreads();
  if (w == 0) {
    const float inv_nx = 1.0f / fmaxf(sqrtf(nacc), 1e-12f);
    float m1 = -1e30f, m2 = -1e30f, m3 = -1e30f;
    int i1 = 0, i2 = 0;
    for (int e = 0; e < NEXP; ++e) {
      float l = lgs[lane][e] * inv_nx;
      if (l > m1)      { m3 = m2; m2 = m1; i2 = i1; m1 = l; i1 = e; }
      else if (l > m2) { m3 = m2; m2 = l; i2 = e; }
      else if (l > m3) { m3 = l; }
    }
    float Z = 0.f;
    for (int e = 0; e < NEXP; ++e) Z += expf(lgs[lane][e] * inv_nx - m1);
    const float p1w = 1.0f / Z;
    const float p2w = expf(m2 - m1) / Z;
    const float s   = p1w + p2w + 1e-9f;
    const int tg = t0 + lane;
    out[tg * 2 + 0] = (float)i1;
    out[tg * 2 + 1] = (float)i2;
    out[2 * NTOK + tg * 2 + 0] = p1w / s;
    out[2 * NTOK + tg * 2 + 1] = p2w / s;
    route[tg] = i1;
    if ((m1 - m2) < TAU || (m2 - m3) < TAU) {
      int idx = atomicAdd(nflag, 1);
      flags[idx] = tg;
    }
  }
}

__global__ __launch_bounds__(512)
void segsum_kernel(const float* __restrict__ x, const int* __restrict__ route,
                   float* __restrict__ sums, int* __restrict__ counts) {
  __shared__ float ls[NEXP * 256];
  __shared__ int lcnt[NEXP];
  const int tid  = threadIdx.x;
  const int lane = tid & 63;
  const int w    = tid >> 6;
  const int hc   = blockIdx.x & 7;
  const int tg   = blockIdx.x >> 3;
  const int hb   = hc * 256;
  #pragma unroll
  for (int i = 0; i < 32; ++i) ls[tid + i * 512] = 0.f;
  if (tid < NEXP) lcnt[tid] = 0;
  __syncthreads();
  const int tbase = tg * 512 + w * 64;
  #pragma unroll 4
  for (int i = 0; i < 64; ++i) {
    const int t = tbase + i;
    const int e = route[t];
    const float* xr = x + (size_t)t * HDIM + hb + lane;
    #pragma unroll
    for (int j = 0; j < 4; ++j)
      atomicAdd(&ls[e * 256 + lane + 64 * j], xr[64 * j]);
    if (hc == 0 && lane == 0) atomicAdd(&lcnt[e], 1);
  }
  __syncthreads();
  #pragma unroll
  for (int i = tid; i < NEXP * 256; i += 512) {
    const int e = i >> 8, h = i & 255;
    atomicAdd(&sums[e * HDIM + hb + h], ls[i]);
  }
  if (hc == 0 && tid < NEXP && lcnt[tid] > 0) atomicAdd(&counts[tid], lcnt[tid]);
}

extern "C" void kernel_launch(void* const* d_in, const int* in_sizes, int n_in,
                              void* d_out, int out_size, void* d_ws, size_t ws_size,
                              hipStream_t stream) {
  const float* x = (const float*)d_in[0];
  const float* c = (const float*)d_in[1];
  float* out = (float*)d_out;
  float* ws = (float*)d_ws;

  float* inv_nc = ws;
  int*   counts = (int*)(ws + 64);      // == cursor
  int*   nflag  = (int*)(ws + 128);
  int*   route  = (int*)(ws + 192);
  int*   flags  = (int*)(ws + 16576);
  float* sums   = ws + 32960;
  float* xnorm2 = ws + 164032;
  float* logits = ws + 180416;
  float* bn     = ws + 1228992;
  int*   bucket = (int*)(ws + 1360064);

  const size_t NEED = 1491136ull * 4ull;
  if (ws_size >= NEED) {
    zero_kernel<<<1, 256, 0, stream>>>(ws + 64, 128);                 // cursor+nflag
    zero_kernel<<<4160, 256, 0, stream>>>(ws + 164032, 1064960);      // xnorm2+logits
    cnorm_kernel<<<NEXP, 256, 0, stream>>>(c, inv_nc);
    cnormalize_kernel<<<NEXP, 256, 0, stream>>>(c, bn);
    gemm_kernel<<<512, 256, 0, stream>>>(x, c, logits, xnorm2);
    softmax_kernel<<<NTOK / 64, 64, 0, stream>>>(logits, xnorm2, inv_nc, out, route, nflag, flags);
    refine_np_kernel<<<512, 256, 0, stream>>>(x, bn, out, route, nflag, flags);
    scatter_kernel<<<64, 256, 0, stream>>>(route, counts, bucket);
    segsum_dense<<<512, 256, 0, stream>>>(x, counts, bucket, sums);
    finalize_kernel<<<NEXP, 256, 0, stream>>>(c, sums, counts, out);
  } else {
    zero_kernel<<<1, 256, 0, stream>>>(ws + 64, 128);
    zero_kernel<<<512, 256, 0, stream>>>(sums, 131072);
    cnorm_kernel<<<NEXP, 256, 0, stream>>>(c, inv_nc);
    router_kernel<<<NTOK / 64, 256, 0, stream>>>(x, c, inv_nc, out, route, nflag, flags);
    refine_np_slow<<<1024, 64, 0, stream>>>(x, c, out, route, nflag, flags);
    segsum_kernel<<<256, 512, 0, stream>>>(x, route, sums, counts);
    finalize_kernel<<<NEXP, 256, 0, stream>>>(c, sums, counts, out);
  }
}

// Round 4
// 314.624 us; speedup vs baseline: 1.0335x; 1.0040x over previous
//
#include <hip/hip_runtime.h>
#include <math.h>

#define NTOK 16384
#define HDIM 2048
#define NEXP 64
#define KK   32
#define TAU  5e-5f
#define MAXB 2048    // bucket capacity per expert (mean 256, 112 sigma margin)
#define TB   32      // tokens per fused block
#define TPAD 36      // lg row stride (tokens + pad)

typedef __attribute__((ext_vector_type(8))) short short8;
typedef __attribute__((ext_vector_type(4))) float f32x4;
typedef __attribute__((ext_vector_type(2))) unsigned int uint2v;

// ws layout (4-byte units):
// [0..64)              inv_nc (f32)
// [64..128)            counts/cursor (i32)
// [128..192)           nflag + pad (i32)
// [192..16576)         route  (i32)
// [16576..32960)       flags  (i32)
// [32960..164032)      sums   (f32, 64x2048)
// [164032..295104)     bn     (f32, 64x2048)
// [295104..360640)     cbh    (u16, 64x2048 = 65536 units)  bf16-hi of c
// [360640..426176)     cbl    (u16, 64x2048 = 65536 units)  bf16-lo of c
// [426176..557248)     bucket (i32, 64x2048)   total ~2.23 MB

__global__ __launch_bounds__(256)
void zero_kernel(float* p, int n) {
  int i = blockIdx.x * 256 + threadIdx.x;
  if (i < n) p[i] = 0.0f;
}

__device__ __forceinline__ float block_reduce_sum(float v, float* red) {
  #pragma unroll
  for (int o = 32; o > 0; o >>= 1) v += __shfl_down(v, o, 64);
  int lane = threadIdx.x & 63;
  int wid  = threadIdx.x >> 6;
  if (lane == 0) red[wid] = v;
  __syncthreads();
  float s = red[0] + red[1] + red[2] + red[3];
  __syncthreads();
  return s;
}

__device__ __forceinline__ double block_reduce_sum_f64(double v, double* red) {
  const int tid = threadIdx.x;
  red[tid] = v;
  __syncthreads();
  if (tid < 128) red[tid] += red[tid + 128];
  __syncthreads();
  if (tid < 64)  red[tid] += red[tid + 64];
  __syncthreads();
  double s = 0.0;
  if (tid < 64) {
    s = red[tid];
    #pragma unroll
    for (int o = 32; o > 0; o >>= 1) s += __shfl_down(s, o, 64);
  }
  if (tid == 0) red[0] = s;
  __syncthreads();
  s = red[0];
  __syncthreads();
  return s;
}

__global__ __launch_bounds__(256)
void cnorm_kernel(const float* __restrict__ c, float* __restrict__ inv_nc) {
  __shared__ float red[4];
  int e = blockIdx.x;
  float ss = 0.f;
  #pragma unroll
  for (int j = 0; j < 8; ++j) {
    float v = c[e * HDIM + threadIdx.x + j * 256];
    ss += v * v;
  }
  float tot = block_reduce_sum(ss, red);
  if (threadIdx.x == 0) inv_nc[e] = 1.0f / fmaxf(sqrtf(tot), 1e-12f);
}

// Center prep: fp32 inv-norm (softmax scale), fp64 bn (refine reference),
// and bf16 hi/lo split of raw c (GEMM B operand), all in one pass.
__global__ __launch_bounds__(256)
void cprep_kernel(const float* __restrict__ c, float* __restrict__ inv_nc,
                  float* __restrict__ bn, unsigned short* __restrict__ cbh,
                  unsigned short* __restrict__ cbl) {
  __shared__ float red[4];
  __shared__ double redd[256];
  __shared__ float s_nc;
  const int e = blockIdx.x;
  const int tid = threadIdx.x;
  const float* cr = c + (size_t)e * HDIM;
  float ss = 0.f;
  double acc = 0.0;
  #pragma unroll
  for (int j = 0; j < 8; ++j) {
    float v = cr[tid + j * 256];
    ss += v * v;
    double dv = (double)v;
    acc += dv * dv;
  }
  float tot = block_reduce_sum(ss, red);
  double cn = block_reduce_sum_f64(acc, redd);
  if (tid == 0) {
    inv_nc[e] = 1.0f / fmaxf(sqrtf(tot), 1e-12f);
    s_nc = (float)fmax(sqrt(cn), 1e-12);
  }
  __syncthreads();
  const double nc = (double)s_nc;
  #pragma unroll
  for (int j = 0; j < 8; ++j) {
    const int k = tid + j * 256;
    const float v = cr[k];
    bn[(size_t)e * HDIM + k] = (float)((double)v / nc);
    unsigned u = __float_as_uint(v);
    unsigned h = u & 0xffff0000u;
    float r = v - __uint_as_float(h);
    cbh[(size_t)e * HDIM + k] = (unsigned short)(u >> 16);
    cbl[(size_t)e * HDIM + k] = (unsigned short)(__float_as_uint(r) >> 16);
  }
}

// split fp32 pair into bf16 hi (truncation) + bf16 lo (truncated residual), packed 2-wide.
__device__ __forceinline__ void cvt2(float v0, float v1, unsigned &hi, unsigned &lo) {
  unsigned u0 = __float_as_uint(v0);
  unsigned u1 = __float_as_uint(v1);
  unsigned h0 = u0 & 0xffff0000u;
  unsigned h1 = u1 & 0xffff0000u;
  float r0 = v0 - __uint_as_float(h0);
  float r1 = v1 - __uint_as_float(h1);
  hi = (u0 >> 16) | h1;
  lo = (__float_as_uint(r0) >> 16) | (__float_as_uint(r1) & 0xffff0000u);
}

// Fused full-K router: 32 tokens x 64 experts x K=2048 per block.
// bf16x3 MFMA logits -> in-LDS softmax/top-2 -> out/route/flags.
// No global logits, no xnorm2, no atomics except nflag.
__global__ __launch_bounds__(256)
void fused_kernel(const float* __restrict__ x,
                  const unsigned short* __restrict__ cbh,
                  const unsigned short* __restrict__ cbl,
                  const float* __restrict__ inv_nc,
                  float* __restrict__ out, int* __restrict__ route,
                  int* __restrict__ nflag, int* __restrict__ flags) {
  __shared__ __align__(16) unsigned short Ah[2][TB][32];     // 4 KB
  __shared__ __align__(16) unsigned short Al[2][TB][32];     // 4 KB
  __shared__ __align__(16) unsigned short Bh[2][NEXP][32];   // 8 KB
  __shared__ __align__(16) unsigned short Bl[2][NEXP][32];   // 8 KB
  __shared__ float lg[NEXP][TPAD];                           // 9 KB
  __shared__ float xn_lds[TB];
  __shared__ float snc[NEXP];

  const int tid  = threadIdx.x;
  const int t0   = blockIdx.x * TB;
  const int sr   = tid >> 3;          // A stage row (0..31), 8 threads/row
  const int sq   = (tid & 7) * 4;     // A stage col (f32x4)
  const int er   = tid >> 2;          // B stage row (0..63), 4 threads/row
  const int eq   = (tid & 3) * 8;     // B stage col (short8)
  const int lane = tid & 63;
  const int w    = tid >> 6;
  const int m16  = (w & 1) * 16;      // wave's token tile
  const int nh32 = (w >> 1) * 32;     // wave's expert half
  const int fr   = lane & 15;
  const int fk   = (lane >> 4) * 8;

  if (tid < NEXP) snc[tid] = inv_nc[tid];

  const float* xptr = x + (size_t)(t0 + sr) * HDIM + sq;
  const unsigned short* bhptr = cbh + (size_t)er * HDIM + eq;
  const unsigned short* blptr = cbl + (size_t)er * HDIM + eq;

  f32x4 xp;
  short8 bhp, blp;
  float nacc = 0.f;

  auto stage = [&](int b) {
    unsigned h01, l01, h23, l23;
    cvt2(xp.x, xp.y, h01, l01);
    cvt2(xp.z, xp.w, h23, l23);
    *(uint2v*)&Ah[b][sr][sq] = (uint2v){h01, h23};
    *(uint2v*)&Al[b][sr][sq] = (uint2v){l01, l23};
    nacc += xp.x*xp.x + xp.y*xp.y + xp.z*xp.z + xp.w*xp.w;
    *(short8*)&Bh[b][er][eq] = bhp;
    *(short8*)&Bl[b][er][eq] = blp;
  };

  // prologue: stage tile 0, preload tile 1
  xp  = *(const f32x4*)(xptr);
  bhp = *(const short8*)(bhptr);
  blp = *(const short8*)(blptr);
  stage(0);
  xp  = *(const f32x4*)(xptr + KK);
  bhp = *(const short8*)(bhptr + KK);
  blp = *(const short8*)(blptr + KK);
  __syncthreads();

  f32x4 acc0 = (f32x4){0.f, 0.f, 0.f, 0.f};
  f32x4 acc1 = (f32x4){0.f, 0.f, 0.f, 0.f};

  for (int it = 0; it < 64; ++it) {
    const int cur = it & 1;
    short8 ah  = *(const short8*)&Ah[cur][m16 + fr][fk];
    short8 al  = *(const short8*)&Al[cur][m16 + fr][fk];
    short8 bh0 = *(const short8*)&Bh[cur][nh32 + fr][fk];
    short8 bl0 = *(const short8*)&Bl[cur][nh32 + fr][fk];
    short8 bh1 = *(const short8*)&Bh[cur][nh32 + 16 + fr][fk];
    short8 bl1 = *(const short8*)&Bl[cur][nh32 + 16 + fr][fk];
    if (it < 63) {
      stage(cur ^ 1);
      if (it < 62) {
        const int off = (it + 2) * KK;
        xp  = *(const f32x4*)(xptr + off);
        bhp = *(const short8*)(bhptr + off);
        blp = *(const short8*)(blptr + off);
      }
    }
    acc0 = __builtin_amdgcn_mfma_f32_16x16x32_bf16(ah, bh0, acc0, 0, 0, 0);
    acc0 = __builtin_amdgcn_mfma_f32_16x16x32_bf16(ah, bl0, acc0, 0, 0, 0);
    acc0 = __builtin_amdgcn_mfma_f32_16x16x32_bf16(al, bh0, acc0, 0, 0, 0);
    acc1 = __builtin_amdgcn_mfma_f32_16x16x32_bf16(ah, bh1, acc1, 0, 0, 0);
    acc1 = __builtin_amdgcn_mfma_f32_16x16x32_bf16(ah, bl1, acc1, 0, 0, 0);
    acc1 = __builtin_amdgcn_mfma_f32_16x16x32_bf16(al, bh1, acc1, 0, 0, 0);
    __syncthreads();
  }

  // token norms: reduce the 8 staging threads of each row (contiguous lanes)
  float s = nacc;
  s += __shfl_xor(s, 1, 64);
  s += __shfl_xor(s, 2, 64);
  s += __shfl_xor(s, 4, 64);
  if ((tid & 7) == 0) xn_lds[sr] = s;

  // logits -> LDS [e][t]; D frag: col(expert)=lane&15, row(token)=(lane>>4)*4+reg
  const int tb = m16 + (lane >> 4) * 4;
  *(f32x4*)&lg[nh32 + fr][tb]      = acc0;
  *(f32x4*)&lg[nh32 + 16 + fr][tb] = acc1;
  __syncthreads();

  if (tid < TB) {
    const int t  = tid;
    const int tg = t0 + t;
    const float inv_nx = 1.0f / fmaxf(sqrtf(xn_lds[t]), 1e-12f);
    float m1 = -1e30f, m2 = -1e30f, m3 = -1e30f;
    int i1 = 0, i2 = 0;
    #pragma unroll
    for (int e = 0; e < NEXP; ++e) {
      float l = lg[e][t] * snc[e] * inv_nx;
      if (l > m1)      { m3 = m2; m2 = m1; i2 = i1; m1 = l; i1 = e; }
      else if (l > m2) { m3 = m2; m2 = l; i2 = e; }
      else if (l > m3) { m3 = l; }
    }
    float Z = 0.f;
    #pragma unroll
    for (int e = 0; e < NEXP; ++e)
      Z += expf(lg[e][t] * snc[e] * inv_nx - m1);
    const float p1w = 1.0f / Z;
    const float p2w = expf(m2 - m1) / Z;
    const float s2  = p1w + p2w + 1e-9f;
    out[tg * 2 + 0] = (float)i1;
    out[tg * 2 + 1] = (float)i2;
    out[2 * NTOK + tg * 2 + 0] = p1w / s2;
    out[2 * NTOK + tg * 2 + 1] = p2w / s2;
    route[tg] = i1;
    if ((m1 - m2) < TAU || (m2 - m3) < TAU) {
      int idx = atomicAdd(nflag, 1);
      flags[idx] = tg;
    }
  }
}

// Refine v2 (R8, known-good): block per flagged token.
__global__ __launch_bounds__(256)
void refine_np_kernel(const float* __restrict__ x, const float* __restrict__ bn,
                      float* __restrict__ out, int* __restrict__ route,
                      const int* __restrict__ nflag, const int* __restrict__ flags) {
  __shared__ float a_lds[HDIM];
  __shared__ double redd[256];
  __shared__ float lf[NEXP];
  __shared__ float s_nx;
  const int tid  = threadIdx.x;
  const int lane = tid & 63;
  const int w    = tid >> 6;
  const int n = *nflag;
  for (int j = blockIdx.x; j < n; j += gridDim.x) {
    const int t = flags[j];
    const float* xr = x + (size_t)t * HDIM;
    double xacc = 0.0;
    #pragma unroll
    for (int i = 0; i < 8; ++i) {
      double v = (double)xr[tid + 256 * i];
      xacc += v * v;
    }
    double xn = block_reduce_sum_f64(xacc, redd);
    if (tid == 0) s_nx = (float)fmax(sqrt(xn), 1e-12);
    __syncthreads();
    const double nx = (double)s_nx;
    #pragma unroll
    for (int i = 0; i < 8; ++i) {
      int k = tid + 256 * i;
      a_lds[k] = (float)((double)xr[k] / nx);
    }
    __syncthreads();
    #pragma unroll 1
    for (int ei = 0; ei < 16; ++ei) {
      const int e = w * 16 + ei;
      const float* br = bn + (size_t)e * HDIM;
      double d = 0.0;
      #pragma unroll 8
      for (int i = 0; i < 32; ++i) {
        int k = lane + 64 * i;
        d += (double)a_lds[k] * (double)br[k];
      }
      #pragma unroll
      for (int o = 32; o > 0; o >>= 1) d += __shfl_down(d, o, 64);
      if (lane == 0) lf[e] = (float)d;
    }
    __syncthreads();
    if (tid == 0) {
      float m32 = lf[0];
      for (int ee = 1; ee < NEXP; ++ee) m32 = fmaxf(m32, lf[ee]);
      float ex[NEXP];
      for (int ee = 0; ee < NEXP; ++ee)
        ex[ee] = (float)exp((double)(lf[ee] - m32));
      float r[8];
      #pragma unroll
      for (int q = 0; q < 8; ++q) r[q] = ex[q];
      for (int i = 8; i < NEXP; i += 8)
        #pragma unroll
        for (int q = 0; q < 8; ++q) r[q] += ex[i + q];
      const float Z = ((r[0] + r[1]) + (r[2] + r[3])) + ((r[4] + r[5]) + (r[6] + r[7]));
      float p1 = -1.f, p2 = -1.f;
      int i1 = 0, i2 = 0;
      for (int ee = 0; ee < NEXP; ++ee) {
        float p = ex[ee] / Z;
        if (p > p1)      { p2 = p1; i2 = i1; p1 = p; i1 = ee; }
        else if (p > p2) { p2 = p; i2 = ee; }
      }
      const float s = (p1 + p2) + 1e-9f;
      out[t * 2 + 0] = (float)i1;
      out[t * 2 + 1] = (float)i2;
      out[2 * NTOK + t * 2 + 0] = p1 / s;
      out[2 * NTOK + t * 2 + 1] = p2 / s;
      route[t] = i1;
    }
    __syncthreads();
  }
}

// slow fallback refine (no bn dependency) for small-ws path
__global__ __launch_bounds__(64)
void refine_np_slow(const float* __restrict__ x, const float* __restrict__ c,
                    float* __restrict__ out, int* __restrict__ route,
                    const int* __restrict__ nflag, const int* __restrict__ flags) {
  __shared__ float lf[NEXP];
  const int e = threadIdx.x;
  const int n = *nflag;
  for (int j = blockIdx.x; j < n; j += gridDim.x) {
    const int t = flags[j];
    const float* xr = x + (size_t)t * HDIM;
    const float* cr = c + (size_t)e * HDIM;
    double xn = 0.0, cn = 0.0;
    for (int k = 0; k < HDIM; ++k) {
      double xv = (double)xr[k];
      double cv = (double)cr[k];
      xn += xv * xv;
      cn += cv * cv;
    }
    const float nx32 = (float)fmax(sqrt(xn), 1e-12);
    const float nc32 = (float)fmax(sqrt(cn), 1e-12);
    double d = 0.0;
    for (int k = 0; k < HDIM; ++k) {
      float a = (float)((double)xr[k] / (double)nx32);
      float b = (float)((double)cr[k] / (double)nc32);
      d += (double)a * (double)b;
    }
    lf[e] = (float)d;
    __syncthreads();
    if (e == 0) {
      float m32 = lf[0];
      for (int ee = 1; ee < NEXP; ++ee) m32 = fmaxf(m32, lf[ee]);
      float ex[NEXP];
      for (int ee = 0; ee < NEXP; ++ee)
        ex[ee] = (float)exp((double)(lf[ee] - m32));
      float r[8];
      #pragma unroll
      for (int q = 0; q < 8; ++q) r[q] = ex[q];
      for (int i = 8; i < NEXP; i += 8)
        #pragma unroll
        for (int q = 0; q < 8; ++q) r[q] += ex[i + q];
      const float Z = ((r[0] + r[1]) + (r[2] + r[3])) + ((r[4] + r[5]) + (r[6] + r[7]));
      float p1 = -1.f, p2 = -1.f;
      int i1 = 0, i2 = 0;
      for (int ee = 0; ee < NEXP; ++ee) {
        float p = ex[ee] / Z;
        if (p > p1)      { p2 = p1; i2 = i1; p1 = p; i1 = ee; }
        else if (p > p2) { p2 = p; i2 = ee; }
      }
      const float s = (p1 + p2) + 1e-9f;
      out[t * 2 + 0] = (float)i1;
      out[t * 2 + 1] = (float)i2;
      out[2 * NTOK + t * 2 + 0] = p1 / s;
      out[2 * NTOK + t * 2 + 1] = p2 / s;
      route[t] = i1;
    }
    __syncthreads();
  }
}

// Bucket scatter: cursor[e] counts tokens (== counts), bucket[e][pos] = t.
// Must run AFTER refine (refine can flip route).
__global__ __launch_bounds__(256)
void scatter_kernel(const int* __restrict__ route, int* __restrict__ cursor,
                    int* __restrict__ bucket) {
  const int t = blockIdx.x * 256 + threadIdx.x;
  const int e = route[t];
  const int pos = atomicAdd(&cursor[e], 1);
  if (pos < MAXB) bucket[e * MAXB + pos] = t;
}

// Dense per-expert sum: block = (expert, h-chunk). No atomics, direct store.
__global__ __launch_bounds__(256)
void segsum_dense(const float* __restrict__ x, const int* __restrict__ cursor,
                  const int* __restrict__ bucket, float* __restrict__ sums) {
  __shared__ int ts[MAXB];
  const int e   = blockIdx.x >> 3;
  const int hc  = blockIdx.x & 7;
  const int hb  = hc * 256;
  const int tid = threadIdx.x;
  int n = cursor[e];
  if (n > MAXB) n = MAXB;
  for (int i = tid; i < n; i += 256) ts[i] = bucket[e * MAXB + i];
  __syncthreads();
  float a[8];
  #pragma unroll
  for (int q = 0; q < 8; ++q) a[q] = 0.f;
  int i = 0;
  for (; i + 7 < n; i += 8) {
    #pragma unroll
    for (int q = 0; q < 8; ++q)
      a[q] += x[(size_t)ts[i + q] * HDIM + hb + tid];
  }
  for (; i < n; ++i) a[0] += x[(size_t)ts[i] * HDIM + hb + tid];
  const float s = ((a[0] + a[1]) + (a[2] + a[3])) + ((a[4] + a[5]) + (a[6] + a[7]));
  sums[e * HDIM + hb + tid] = s;
}

__global__ __launch_bounds__(256)
void finalize_kernel(const float* __restrict__ c, const float* __restrict__ sums,
                     const int* __restrict__ counts, float* __restrict__ out) {
  __shared__ float red[4];
  const int e = blockIdx.x;
  const int tid = threadIdx.x;
  const float cnt = (float)counts[e];
  const float minv = 1.0f / (cnt + 1e-6f);
  float u[8], cv[8];
  float ss = 0.f;
  #pragma unroll
  for (int j = 0; j < 8; ++j) {
    int h = tid + j * 256;
    cv[j] = c[e * HDIM + h];
    float mean = sums[e * HDIM + h] * minv;
    u[j] = 0.9f * cv[j] + 0.1f * mean;
    ss += u[j] * u[j];
  }
  float tot = block_reduce_sum(ss, red);
  float sc = 1.0f / fmaxf(sqrtf(tot), 1e-12f);
  const bool nz = cnt > 0.f;
  #pragma unroll
  for (int j = 0; j < 8; ++j) {
    int h = tid + j * 256;
    out[4 * NTOK + e * HDIM + h] = nz ? u[j] * sc : cv[j];
  }
}

// ---- fallback path kernels (small ws): R5 router + old segsum ----
__global__ __launch_bounds__(256)
void router_kernel(const float* __restrict__ x, const float* __restrict__ c,
                   const float* __restrict__ inv_nc, float* __restrict__ out,
                   int* __restrict__ route, int* __restrict__ nflag,
                   int* __restrict__ flags) {
  __shared__ __align__(16) float xs[64][36];
  __shared__ float lgs[64][67];
  const int tid  = threadIdx.x;
  const int lane = tid & 63;
  const int w    = tid >> 6;
  const int t0   = blockIdx.x * 64;
  const int e0   = __builtin_amdgcn_readfirstlane(w * 16);
  const float* cb = c + (size_t)e0 * HDIM;
  const int st = tid >> 3;
  const int sk = (tid & 7) * 4;
  float acc[16];
  #pragma unroll
  for (int e = 0; e < 16; ++e) acc[e] = 0.f;
  float nacc = 0.f;
  float4 p0 = *(const float4*)&x[(size_t)(t0 + st)      * HDIM + sk];
  float4 p1 = *(const float4*)&x[(size_t)(t0 + st + 32) * HDIM + sk];
  for (int k0 = 0; k0 < HDIM; k0 += 32) {
    __syncthreads();
    *(float4*)&xs[st][sk]      = p0;
    *(float4*)&xs[st + 32][sk] = p1;
    __syncthreads();
    const int kn = k0 + 32;
    if (kn < HDIM) {
      p0 = *(const float4*)&x[(size_t)(t0 + st)      * HDIM + kn + sk];
      p1 = *(const float4*)&x[(size_t)(t0 + st + 32) * HDIM + kn + sk];
    }
    float a[32];
    #pragma unroll
    for (int j = 0; j < 32; j += 4) {
      float4 v = *(const float4*)&xs[lane][j];
      a[j] = v.x; a[j+1] = v.y; a[j+2] = v.z; a[j+3] = v.w;
    }
    if (w == 0) {
      #pragma unroll
      for (int j = 0; j < 32; ++j) nacc += a[j] * a[j];
    }
    #pragma unroll
    for (int e = 0; e < 16; ++e) {
      const float* br = cb + (size_t)e * HDIM + k0;
      #pragma unroll
      for (int j = 0; j < 32; j += 4) {
        float4 bv = *(const float4*)&br[j];
        acc[e] += a[j]*bv.x + a[j+1]*bv.y + a[j+2]*bv.z + a[j+3]*bv.w;
      }
    }
  }
  #pragma unroll
  for (int e = 0; e < 16; ++e) lgs[lane][e0 + e] = acc[e] * inv_nc[e0 + e];
  __syncthreads();
  if (w == 0) {
    const float inv_nx = 1.0f / fmaxf(sqrtf(nacc), 1e-12f);
    float m1 = -1e30f, m2 = -1e30f, m3 = -1e30f;
    int i1 = 0, i2 = 0;
    for (int e = 0; e < NEXP; ++e) {
      float l = lgs[lane][e] * inv_nx;
      if (l > m1)      { m3 = m2; m2 = m1; i2 = i1; m1 = l; i1 = e; }
      else if (l > m2) { m3 = m2; m2 = l; i2 = e; }
      else if (l > m3) { m3 = l; }
    }
    float Z = 0.f;
    for (int e = 0; e < NEXP; ++e) Z += expf(lgs[lane][e] * inv_nx - m1);
    const float p1w = 1.0f / Z;
    const float p2w = expf(m2 - m1) / Z;
    const float s   = p1w + p2w + 1e-9f;
    const int tg = t0 + lane;
    out[tg * 2 + 0] = (float)i1;
    out[tg * 2 + 1] = (float)i2;
    out[2 * NTOK + tg * 2 + 0] = p1w / s;
    out[2 * NTOK + tg * 2 + 1] = p2w / s;
    route[tg] = i1;
    if ((m1 - m2) < TAU || (m2 - m3) < TAU) {
      int idx = atomicAdd(nflag, 1);
      flags[idx] = tg;
    }
  }
}

__global__ __launch_bounds__(512)
void segsum_kernel(const float* __restrict__ x, const int* __restrict__ route,
                   float* __restrict__ sums, int* __restrict__ counts) {
  __shared__ float ls[NEXP * 256];
  __shared__ int lcnt[NEXP];
  const int tid  = threadIdx.x;
  const int lane = tid & 63;
  const int w    = tid >> 6;
  const int hc   = blockIdx.x & 7;
  const int tg   = blockIdx.x >> 3;
  const int hb   = hc * 256;
  #pragma unroll
  for (int i = 0; i < 32; ++i) ls[tid + i * 512] = 0.f;
  if (tid < NEXP) lcnt[tid] = 0;
  __syncthreads();
  const int tbase = tg * 512 + w * 64;
  #pragma unroll 4
  for (int i = 0; i < 64; ++i) {
    const int t = tbase + i;
    const int e = route[t];
    const float* xr = x + (size_t)t * HDIM + hb + lane;
    #pragma unroll
    for (int j = 0; j < 4; ++j)
      atomicAdd(&ls[e * 256 + lane + 64 * j], xr[64 * j]);
    if (hc == 0 && lane == 0) atomicAdd(&lcnt[e], 1);
  }
  __syncthreads();
  #pragma unroll
  for (int i = tid; i < NEXP * 256; i += 512) {
    const int e = i >> 8, h = i & 255;
    atomicAdd(&sums[e * HDIM + hb + h], ls[i]);
  }
  if (hc == 0 && tid < NEXP && lcnt[tid] > 0) atomicAdd(&counts[tid], lcnt[tid]);
}

extern "C" void kernel_launch(void* const* d_in, const int* in_sizes, int n_in,
                              void* d_out, int out_size, void* d_ws, size_t ws_size,
                              hipStream_t stream) {
  const float* x = (const float*)d_in[0];
  const float* c = (const float*)d_in[1];
  float* out = (float*)d_out;
  float* ws = (float*)d_ws;

  float* inv_nc = ws;
  int*   counts = (int*)(ws + 64);      // == cursor
  int*   nflag  = (int*)(ws + 128);
  int*   route  = (int*)(ws + 192);
  int*   flags  = (int*)(ws + 16576);
  float* sums   = ws + 32960;
  float* bn     = ws + 164032;
  unsigned short* cbh = (unsigned short*)(ws + 295104);
  unsigned short* cbl = (unsigned short*)(ws + 360640);
  int*   bucket = (int*)(ws + 426176);

  const size_t NEED = 557248ull * 4ull;
  if (ws_size >= NEED) {
    zero_kernel<<<1, 256, 0, stream>>>(ws + 64, 128);                 // cursor+nflag
    cprep_kernel<<<NEXP, 256, 0, stream>>>(c, inv_nc, bn, cbh, cbl);
    fused_kernel<<<NTOK / TB, 256, 0, stream>>>(x, cbh, cbl, inv_nc, out, route, nflag, flags);
    refine_np_kernel<<<512, 256, 0, stream>>>(x, bn, out, route, nflag, flags);
    scatter_kernel<<<64, 256, 0, stream>>>(route, counts, bucket);
    segsum_dense<<<512, 256, 0, stream>>>(x, counts, bucket, sums);
    finalize_kernel<<<NEXP, 256, 0, stream>>>(c, sums, counts, out);
  } else {
    zero_kernel<<<1, 256, 0, stream>>>(ws + 64, 128);
    zero_kernel<<<512, 256, 0, stream>>>(sums, 131072);
    cnorm_kernel<<<NEXP, 256, 0, stream>>>(c, inv_nc);
    router_kernel<<<NTOK / 64, 256, 0, stream>>>(x, c, inv_nc, out, route, nflag, flags);
    refine_np_slow<<<1024, 64, 0, stream>>>(x, c, out, route, nflag, flags);
    segsum_kernel<<<256, 512, 0, stream>>>(x, route, sums, counts);
    finalize_kernel<<<NEXP, 256, 0, stream>>>(c, sums, counts, out);
  }
}